// Round 15
// baseline (76.045 us; speedup 1.0000x reference)
//
#include <hip/hip_runtime.h>
#include <hip/hip_bf16.h>

typedef __attribute__((ext_vector_type(8))) short bf16x8;
typedef __attribute__((ext_vector_type(4))) float f32x4;
typedef __attribute__((ext_vector_type(16))) float f32x16;
typedef __attribute__((ext_vector_type(4))) unsigned u32x4;

__device__ __forceinline__ unsigned bfbits(float v) {
  __hip_bfloat16 h = __float2bfloat16(v);
  return (unsigned)*reinterpret_cast<unsigned short*>(&h);
}

// ---------------------------------------------------------------------------
// Weight normalization body: one 64-lane wave handles one output row o.
//  wt  [o][(kh*3+kw)*64 + c]        (legacy layout, fallback kernel)
//  wt3 [ks][g=o/32][n=o%32][k16]    (32x32x16 fragment-major)
// ---------------------------------------------------------------------------
__device__ __forceinline__ void wnorm_one(const float* __restrict__ w,
                                          ushort* __restrict__ wt,
                                          ushort* __restrict__ wt3,
                                          int o, int c) {
  float v[9];
  float ss = 0.f;
  const float* row = w + o * 576 + c * 9;
#pragma unroll
  for (int j = 0; j < 9; ++j) { v[j] = row[j]; ss += v[j] * v[j]; }
#pragma unroll
  for (int off = 32; off > 0; off >>= 1) ss += __shfl_xor(ss, off);
  const float inv = 1.0f / fmaxf(sqrtf(ss), 1e-12f);
  const int g = o >> 5, n = o & 31;
#pragma unroll
  for (int j = 0; j < 9; ++j) {
    const ushort bv = (ushort)bfbits(v[j] * inv);
    wt[o * 576 + j * 64 + c] = bv;
    const int ks = j * 4 + (c >> 4);
    wt3[((ks * 8 + g) * 32 + n) * 16 + (c & 15)] = bv;
  }
}

__global__ void wnorm_kernel(const float* __restrict__ w,
                             ushort* __restrict__ wt,
                             ushort* __restrict__ wt3) {
  wnorm_one(w, wt, wt3, blockIdx.x, threadIdx.x);
}

// ---------------------------------------------------------------------------
// Kernel 2: blockIdx.y < 32 : transpose+convert x [B][C][H][W] fp32 ->
//   xt [B][H][cb=8][W][8c] bf16 (c-block-major: 16B granule = 8 channels of
//   one x; granules contiguous along x) and css[B][H][W] = sum_c x^2.
// blockIdx.y == 32 : fused weight normalization (4 waves -> 4 o rows).
// ---------------------------------------------------------------------------
__global__ __launch_bounds__(256, 8) void xprep_kernel(
    const float* __restrict__ x, ushort* __restrict__ xt,
    float* __restrict__ css, const float* __restrict__ w,
    ushort* __restrict__ wt, ushort* __restrict__ wt3) {
  __shared__ __align__(16) unsigned tile[64 * 33];  // [x][c2] padded stride 33
  __shared__ __align__(16) float cssp[4 * 64];
  const int t = threadIdx.x;
  if (blockIdx.y == 32) {
    wnorm_one(w, wt, wt3, blockIdx.x * 4 + (t >> 6), t & 63);
    return;
  }
  const int y = blockIdx.x, b = blockIdx.y;
  const int c = t >> 2, m = t & 3;
  const int lane = t & 63, wv = t >> 6;

  const float* src = x + (((size_t)b * 64 + c) * 64 + y) * 64 + m * 4;
  float f[16];
#pragma unroll
  for (int j4 = 0; j4 < 4; ++j4) {
    const f32x4 v = *(const f32x4*)(src + j4 * 16);
#pragma unroll
    for (int k = 0; k < 4; ++k) f[j4 * 4 + k] = v[k];
  }
  float s[16];
#pragma unroll
  for (int j = 0; j < 16; ++j) {
    float v = f[j] * f[j];
    v += __shfl_xor(v, 4);
    v += __shfl_xor(v, 8);
    v += __shfl_xor(v, 16);
    v += __shfl_xor(v, 32);
    s[j] = v;
  }
  if (lane < 4) {
#pragma unroll
    for (int j4 = 0; j4 < 4; ++j4) {
      f32x4 v = {s[j4 * 4], s[j4 * 4 + 1], s[j4 * 4 + 2], s[j4 * 4 + 3]};
      *(f32x4*)(cssp + wv * 64 + j4 * 16 + lane * 4) = v;
    }
  }
  const int parity = c & 1;
  const int c2 = c >> 1;
#pragma unroll
  for (int j = 0; j < 16; ++j) {
    const float pf = __shfl_xor(f[j], 4);
    const bool mine = parity ? (j >= 8) : (j < 8);
    if (mine) {
      const unsigned dw = parity ? (bfbits(pf) | (bfbits(f[j]) << 16))
                                 : (bfbits(f[j]) | (bfbits(pf) << 16));
      const int px = (j >> 2) * 16 + m * 4 + (j & 3);
      tile[px * 33 + c2] = dw;
    }
  }
  __syncthreads();
  // write xt c-block-major: granule (cb, x) at ((b*64+y)*8 + cb)*512 + x*8
  {
    const int xr = t & 63, q = t >> 6;
    unsigned d[8];
#pragma unroll
    for (int i = 0; i < 8; ++i) d[i] = tile[xr * 33 + q * 8 + i];
    ushort* dst =
        xt + ((((size_t)b * 64 + y) * 8 + 2 * q) * 64 + xr) * 8;
    u32x4 v0 = {d[0], d[1], d[2], d[3]};
    u32x4 v1 = {d[4], d[5], d[6], d[7]};
    *(u32x4*)dst = v0;
    *(u32x4*)(dst + 512) = v1;  // cb+1 plane
  }
  if (t < 64) {
    const float sum = cssp[t] + cssp[64 + t] + cssp[128 + t] + cssp[192 + t];
    css[((size_t)b * 64 + y) * 64 + t] = sum;
  }
}

// ---------------------------------------------------------------------------
// Main kernel (round-14 K-loop + in-register 2x2 pool epilogue): one block
// per (y0, image). 8 waves = 2(x-half) x 4(N); each wave computes BOTH conv
// rows (acc[mf=image-row][nf], 64 AGPR) for its 32-wide x-half. K-loop cost
// is identical to r14 (2 ds_reads + 2 B-loads + 4 MFMA per step; stride-1
// conflict-free A-reads from the c-block-major xs), but the 2x2 pool is now
// FULLY IN-REGISTER: y-pair = acc[0]+acc[1] in-lane, x-pair = adjacent regs.
// Epilogue = pooled write (2-way banks, no RMW) + ONE barrier + coalesced
// store (was: 3 barriers + cross-wave RMW pass).
// B depth-3 prefetch (r14, neutral-clean); setprio kept (removal regressed,
// r12); no explicit A-dbuf (regressed, r12).
//
// LDS: xs   [4 rows][8 cb][66 cols][16B]                      [0, 33792)
//      pool [32 px][258 floats] transposed                [33792, 66816)
//      invp float[128]                                    [66816, 67328)
// ---------------------------------------------------------------------------
__global__ __launch_bounds__(512, 4) void ckn_main(
    const ushort* __restrict__ xt, const float* __restrict__ css,
    const ushort* __restrict__ wt3, float* __restrict__ out) {
  __shared__ __align__(16) char smem[67328];
  char* const xs = smem;
  float* const pool = (float*)(smem + 33792);
  float* const invp = (float*)(smem + 66816);
  const int PS = 258;

  const int tid = threadIdx.x;
  const int y0 = blockIdx.x;
  const int b = blockIdx.y;

  // ---- invp from css (rows 2y0, 2y0+1 windows), written pre-barrier ----
  if (tid < 128) {
    const int ry = tid >> 6, xx = tid & 63;
    const int yc = 2 * y0 + ry;
    float s = 0.f;
#pragma unroll
    for (int dy = -1; dy <= 1; ++dy) {
      const int yy = yc + dy;
      if ((unsigned)yy < 64u) s += css[((size_t)b * 64 + yy) * 64 + xx];
    }
    const float sl = __shfl_up(s, 1);
    const float sr = __shfl_down(s, 1);
    const float tot = s + ((xx > 0) ? sl : 0.f) + ((xx < 63) ? sr : 0.f);
    invp[tid] = 1.0f / (sqrtf(fmaxf(tot, 0.f)) + 1e-8f);
  }

  // ---- pad columns (col 0 and 65 of every (row, cb) plane) ----
  if (tid < 64) {
    const int r4 = tid >> 4, cb = (tid >> 1) & 7, colsel = tid & 1;
    *(f32x4*)(xs + r4 * 8448 + cb * 1056 + colsel * 65 * 16) =
        (f32x4){0.f, 0.f, 0.f, 0.f};
  }

  // ---- stage 4 rows: wave w stages cb-plane w of each row ----
  {
    const int l = tid & 63;   // col-1
    const int w = tid >> 6;   // cb plane
    const ushort* srcb = xt + (((size_t)b * 64) * 8 + w) * 512 + l * 8;
#pragma unroll
    for (int r4 = 0; r4 < 4; ++r4) {
      const int y_img = 2 * y0 - 1 + r4;
      char* dst = xs + r4 * 8448 + w * 1056 + (l + 1) * 16;
      if ((unsigned)y_img < 64u) {
        const ushort* src = srcb + (size_t)y_img * 4096;
        __builtin_amdgcn_global_load_lds(
            (const __attribute__((address_space(1))) void*)src,
            (__attribute__((address_space(3))) void*)dst, 16, 0, 0);
      } else {
        *(f32x4*)dst = (f32x4){0.f, 0.f, 0.f, 0.f};
      }
    }
  }

  const int lane = tid & 63;
  const int wid = tid >> 6;
  const int wxh = wid & 1;      // x-half (0: x 0..31, 1: x 32..63)
  const int wave_n = wid >> 1;  // 64-wide N chunk
  const int lane31 = lane & 31;
  const int hi = lane >> 5;

  // B base in wt3 (ushort elems): fragment (ks, g) is 512 shorts at
  // (ks*8+g)*512; lane reads 8 shorts at n*16 + hi*8.
  const ushort* wb3 = wt3 + (size_t)lane31 * 16 + hi * 8;
  const int g0 = wave_n * 2;

  // DEPTH-3 B prefetch: ks=0,1,2 issued BEFORE the barrier (overlaps DMA).
  bf16x8 bq[3][2];
#pragma unroll
  for (int d = 0; d < 3; ++d)
#pragma unroll
    for (int nf = 0; nf < 2; ++nf)
      bq[d][nf] = *(const bf16x8*)(wb3 + (size_t)(d * 8 + g0 + nf) * 512);

  // A base addresses: PH[kw] = (wxh*32+lane31+kw)*16 + hi*1056;
  // per-step addr = PH + (mf+kh)*8448 + (ks&3)*2112 (compile-time per step;
  // mf = image row of the pair: conv row 2y0+mf reads staged rows mf..mf+2)
  int PH[3];
#pragma unroll
  for (int kw = 0; kw < 3; ++kw)
    PH[kw] = (wxh * 32 + lane31 + kw) * 16 + hi * 1056;

  __syncthreads();

  f32x16 acc[2][2];
#pragma unroll
  for (int i = 0; i < 2; ++i)
#pragma unroll
    for (int j = 0; j < 2; ++j)
#pragma unroll
      for (int e = 0; e < 16; ++e) acc[i][j][e] = 0.f;

#pragma unroll
  for (int ks = 0; ks < 36; ++ks) {
    const int t9 = ks >> 2;
    const int kh = t9 / 3, kw = t9 % 3;
    const int stepoff = kh * 8448 + (ks & 3) * 2112;  // compile-time const
    const int cur = ks % 3;                            // compile-time const
    bf16x8 afrag[2];
#pragma unroll
    for (int mf = 0; mf < 2; ++mf)
      afrag[mf] = *(const bf16x8*)(xs + PH[kw] + stepoff + mf * 8448);
    __builtin_amdgcn_s_setprio(1);
#pragma unroll
    for (int mf = 0; mf < 2; ++mf)
#pragma unroll
      for (int nf = 0; nf < 2; ++nf)
        acc[mf][nf] = __builtin_amdgcn_mfma_f32_32x32x16_bf16(
            afrag[mf], bq[cur][nf], acc[mf][nf], 0, 0, 0);
    __builtin_amdgcn_s_setprio(0);
    if (ks + 3 < 36) {
#pragma unroll
      for (int nf = 0; nf < 2; ++nf)
        bq[cur][nf] =
            *(const bf16x8*)(wb3 + (size_t)((ks + 3) * 8 + g0 + nf) * 512);
    }
  }

  // ---- epilogue: in-register 2x2 pool, single pool write, ONE barrier ----
  // acc[mf][nf] reg r=4q+j: x = wxh*32 + 8q + 4hi + j (image row 2y0+mf),
  // o = wave_n*64 + nf*32 + lane31. Pooled px = wxh*16 + 4q + 2hi (+pair).
  {
    const int ob = wave_n * 64 + lane31;
#pragma unroll
    for (int q = 0; q < 4; ++q) {
      const f32x4 ip0 = *(const f32x4*)(invp + wxh * 32 + 8 * q + 4 * hi);
      const f32x4 ip1 = *(const f32x4*)(invp + 64 + wxh * 32 + 8 * q + 4 * hi);
      const int px = wxh * 16 + 4 * q + 2 * hi;
#pragma unroll
      for (int nf = 0; nf < 2; ++nf) {
        const float e00 = __expf(acc[0][nf][4 * q + 0] * ip0[0] - 1.f);
        const float e01 = __expf(acc[0][nf][4 * q + 1] * ip0[1] - 1.f);
        const float e02 = __expf(acc[0][nf][4 * q + 2] * ip0[2] - 1.f);
        const float e03 = __expf(acc[0][nf][4 * q + 3] * ip0[3] - 1.f);
        const float e10 = __expf(acc[1][nf][4 * q + 0] * ip1[0] - 1.f);
        const float e11 = __expf(acc[1][nf][4 * q + 1] * ip1[1] - 1.f);
        const float e12 = __expf(acc[1][nf][4 * q + 2] * ip1[2] - 1.f);
        const float e13 = __expf(acc[1][nf][4 * q + 3] * ip1[3] - 1.f);
        pool[px * PS + ob + nf * 32] = 0.25f * ((e00 + e01) + (e10 + e11));
        pool[(px + 1) * PS + ob + nf * 32] =
            0.25f * ((e02 + e03) + (e12 + e13));
      }
    }
  }
  __syncthreads();

  // ---- coalesced store: 8 lanes cover one o-row's full 128B ----
  const size_t obase = (((size_t)b * 256) * 32 + y0) * 32;
#pragma unroll
  for (int j = 0; j < 4; ++j) {
    const int o = j * 64 + (tid >> 3);
    const int ch = (tid & 7) * 4;
    const f32x4 v = {pool[(ch + 0) * PS + o], pool[(ch + 1) * PS + o],
                     pool[(ch + 2) * PS + o], pool[(ch + 3) * PS + o]};
    *(f32x4*)(out + obase + (size_t)o * 1024 + ch) = v;
  }
}

// ---------------------------------------------------------------------------
// Fallback (round-1 kernel, fused transpose in-block) if ws is too small.
// ---------------------------------------------------------------------------
__global__ __launch_bounds__(512, 4) void ckn_main_v1(
    const float* __restrict__ x, const ushort* __restrict__ wt,
    float* __restrict__ out) {
  __shared__ __align__(16) char smem[43552];
  char* const xs = smem;
  float* const invp = (float*)(smem + 33792);
  float* const cs = (float*)(smem + 34304);
  float* const csp = (float*)(smem + 35360);
  float* const pool = (float*)smem;

  const int tid = threadIdx.x;
  const int y0 = blockIdx.x;
  const int b = blockIdx.y;

  if (tid < 64) {
    const int r4 = tid >> 4, colsel = (tid >> 3) & 1, cblk = tid & 7;
    const int col = colsel * 65;
    *(f32x4*)(xs + r4 * 8448 + col * 128 + cblk * 16) =
        (f32x4){0.f, 0.f, 0.f, 0.f};
  }
  {
    const int xx = tid & 63;
    const int cg = tid >> 6;
    const int col = xx + 1;
    const int sw = (cg * 16) ^ ((col & 7) << 4);
#pragma unroll
    for (int r4 = 0; r4 < 4; ++r4) {
      const int y_img = 2 * y0 - 1 + r4;
      char* dst = xs + r4 * 8448 + col * 128 + sw;
      if ((unsigned)y_img < 64u) {
        const float* src =
            x + (((size_t)b * 64 + cg * 8) * 64 + y_img) * 64 + xx;
        float ss = 0.f;
        union { bf16x8 v; ushort u[8]; } pk;
#pragma unroll
        for (int j = 0; j < 8; ++j) {
          const float f = src[(size_t)j * 4096];
          ss += f * f;
          pk.u[j] = (ushort)bfbits(f);
        }
        *(bf16x8*)dst = pk.v;
        csp[(r4 * 8 + cg) * 64 + xx] = ss;
      } else {
        *(bf16x8*)dst = (bf16x8){0, 0, 0, 0, 0, 0, 0, 0};
        csp[(r4 * 8 + cg) * 64 + xx] = 0.f;
      }
    }
  }
  __syncthreads();
  if (tid < 256) {
    const int r4 = tid >> 6, xc = tid & 63;
    float s = 0.f;
#pragma unroll
    for (int cg = 0; cg < 8; ++cg) s += csp[(r4 * 8 + cg) * 64 + xc];
    cs[r4 * 66 + xc + 1] = s;
  }
  if (tid >= 256 && tid < 264) {
    const int t = tid - 256;
    cs[(t >> 1) * 66 + (t & 1) * 65] = 0.f;
  }
  __syncthreads();
  if (tid < 128) {
    const int ry = tid >> 6, xp = tid & 63;
    float s = 0.f;
#pragma unroll
    for (int dr = 0; dr < 3; ++dr)
#pragma unroll
      for (int dc = 0; dc < 3; ++dc) s += cs[(ry + dr) * 66 + xp + dc];
    invp[tid] = 1.0f / (sqrtf(fmaxf(s, 0.f)) + 1e-8f);
  }
  __syncthreads();

  const int lane = tid & 63;
  const int wid = tid >> 6;
  const int wave_m = wid & 1;
  const int wave_n = wid >> 1;
  const int lane16 = lane & 15;
  const int klane = lane >> 4;
  const int o_base = wave_n * 64;

  f32x4 acc[4][4];
#pragma unroll
  for (int i = 0; i < 4; ++i)
#pragma unroll
    for (int j = 0; j < 4; ++j) acc[i][j] = (f32x4){0.f, 0.f, 0.f, 0.f};
  const ushort* wbase = wt + (o_base + lane16) * 576 + klane * 8;
#pragma unroll
  for (int ks = 0; ks < 18; ++ks) {
    const int t9 = ks >> 1;
    const int kh = t9 / 3, kw = t9 % 3;
    const int cb = (ks & 1) * 64 + klane * 16;
    bf16x8 bfrag[4];
#pragma unroll
    for (int fn = 0; fn < 4; ++fn)
      bfrag[fn] = *(const bf16x8*)(wbase + fn * 16 * 576 + ks * 32);
    const int r4 = wave_m + kh;
#pragma unroll
    for (int fm = 0; fm < 4; ++fm) {
      const int col = fm * 16 + lane16 + kw;
      const int addr = r4 * 8448 + col * 128 + (cb ^ ((col & 7) << 4));
      const bf16x8 afrag = *(const bf16x8*)(xs + addr);
#pragma unroll
      for (int fn = 0; fn < 4; ++fn)
        acc[fm][fn] = __builtin_amdgcn_mfma_f32_16x16x32_bf16(
            afrag, bfrag[fn], acc[fm][fn], 0, 0, 0);
    }
  }
  float ep0[4][4], ep1[4][4];
#pragma unroll
  for (int fm = 0; fm < 4; ++fm) {
    const int m = wave_m * 64 + fm * 16 + klane * 4;
    const f32x4 ip = *(const f32x4*)(invp + m);
#pragma unroll
    for (int fn = 0; fn < 4; ++fn) {
      const f32x4 v = acc[fm][fn];
      const float e0 = __expf(v[0] * ip[0] - 1.f);
      const float e1 = __expf(v[1] * ip[1] - 1.f);
      const float e2 = __expf(v[2] * ip[2] - 1.f);
      const float e3 = __expf(v[3] * ip[3] - 1.f);
      ep0[fm][fn] = e0 + e1;
      ep1[fm][fn] = e2 + e3;
    }
  }
  __syncthreads();
  if (wave_m == 1) {
#pragma unroll
    for (int fm = 0; fm < 4; ++fm) {
      const int ox = fm * 8 + klane * 2;
#pragma unroll
      for (int fn = 0; fn < 4; ++fn) {
        const int o = o_base + fn * 16 + lane16;
        *(float2*)(pool + o * 32 + ox) = make_float2(ep0[fm][fn], ep1[fm][fn]);
      }
    }
  }
  __syncthreads();
  if (wave_m == 0) {
#pragma unroll
    for (int fm = 0; fm < 4; ++fm) {
      const int ox = fm * 8 + klane * 2;
#pragma unroll
      for (int fn = 0; fn < 4; ++fn) {
        const int o = o_base + fn * 16 + lane16;
        const float2 othr = *(const float2*)(pool + o * 32 + ox);
        const float r0 = 0.25f * (ep0[fm][fn] + othr.x);
        const float r1 = 0.25f * (ep1[fm][fn] + othr.y);
        *(float2*)(out + ((((size_t)b * 256 + o) * 32 + y0) * 32 + ox)) =
            make_float2(r0, r1);
      }
    }
  }
}

// ---------------------------------------------------------------------------
extern "C" void kernel_launch(void* const* d_in, const int* in_sizes, int n_in,
                              void* d_out, int out_size, void* d_ws,
                              size_t ws_size, hipStream_t stream) {
  const float* x = (const float*)d_in[0];
  const float* w = (const float*)d_in[1];
  float* out = (float*)d_out;

  const size_t XT_BYTES = 32ull * 64 * 64 * 64 * 2;   // 16,777,216
  const size_t CSS_BYTES = 32ull * 64 * 64 * 4;       //    524,288
  const size_t WT_BYTES = 256ull * 576 * 2;           //    294,912
  const size_t NEED = XT_BYTES + CSS_BYTES + 2 * WT_BYTES;

  if (ws_size >= NEED) {
    ushort* xt = (ushort*)d_ws;
    float* css = (float*)((char*)d_ws + XT_BYTES);
    ushort* wt = (ushort*)((char*)d_ws + XT_BYTES + CSS_BYTES);
    ushort* wt3 = (ushort*)((char*)d_ws + XT_BYTES + CSS_BYTES + WT_BYTES);

    xprep_kernel<<<dim3(64, 33), dim3(256), 0, stream>>>(x, xt, css, w, wt,
                                                         wt3);
    ckn_main<<<dim3(32, 32), dim3(512), 0, stream>>>(xt, css, wt3, out);
  } else {
    ushort* wt = (ushort*)d_ws;
    ushort* wt3 = wt + 256 * 576;
    if (ws_size >= 2 * WT_BYTES) {
      wnorm_kernel<<<dim3(256), dim3(64), 0, stream>>>(w, wt, wt3);
      ckn_main_v1<<<dim3(32, 32), dim3(512), 0, stream>>>(x, wt, out);
    }
  }
}

// Round 16
// 64.019 us; speedup vs baseline: 1.1879x; 1.1879x over previous
//
#include <hip/hip_runtime.h>
#include <hip/hip_bf16.h>

typedef __attribute__((ext_vector_type(8))) short bf16x8;
typedef __attribute__((ext_vector_type(4))) float f32x4;
typedef __attribute__((ext_vector_type(16))) float f32x16;
typedef __attribute__((ext_vector_type(4))) unsigned u32x4;

__device__ __forceinline__ unsigned bfbits(float v) {
  __hip_bfloat16 h = __float2bfloat16(v);
  return (unsigned)*reinterpret_cast<unsigned short*>(&h);
}

// ---------------------------------------------------------------------------
// Weight normalization body: one 64-lane wave handles one output row o.
//  wt  [o][(kh*3+kw)*64 + c]        (legacy layout, fallback kernel)
//  wt3 [ks][g=o/32][n=o%32][k16]    (32x32x16 fragment-major)
// ---------------------------------------------------------------------------
__device__ __forceinline__ void wnorm_one(const float* __restrict__ w,
                                          ushort* __restrict__ wt,
                                          ushort* __restrict__ wt3,
                                          int o, int c) {
  float v[9];
  float ss = 0.f;
  const float* row = w + o * 576 + c * 9;
#pragma unroll
  for (int j = 0; j < 9; ++j) { v[j] = row[j]; ss += v[j] * v[j]; }
#pragma unroll
  for (int off = 32; off > 0; off >>= 1) ss += __shfl_xor(ss, off);
  const float inv = 1.0f / fmaxf(sqrtf(ss), 1e-12f);
  const int g = o >> 5, n = o & 31;
#pragma unroll
  for (int j = 0; j < 9; ++j) {
    const ushort bv = (ushort)bfbits(v[j] * inv);
    wt[o * 576 + j * 64 + c] = bv;
    const int ks = j * 4 + (c >> 4);
    wt3[((ks * 8 + g) * 32 + n) * 16 + (c & 15)] = bv;
  }
}

__global__ void wnorm_kernel(const float* __restrict__ w,
                             ushort* __restrict__ wt,
                             ushort* __restrict__ wt3) {
  wnorm_one(w, wt, wt3, blockIdx.x, threadIdx.x);
}

// ---------------------------------------------------------------------------
// Kernel 2: blockIdx.y < 32 : transpose+convert x [B][C][H][W] fp32 ->
//   xt [B][H][cb=8][W][8c] bf16 (c-block-major: 16B granule = 8 channels of
//   one x; granules contiguous along x) and css[B][H][W] = sum_c x^2.
// blockIdx.y == 32 : fused weight normalization (4 waves -> 4 o rows).
// ---------------------------------------------------------------------------
__global__ __launch_bounds__(256, 8) void xprep_kernel(
    const float* __restrict__ x, ushort* __restrict__ xt,
    float* __restrict__ css, const float* __restrict__ w,
    ushort* __restrict__ wt, ushort* __restrict__ wt3) {
  __shared__ __align__(16) unsigned tile[64 * 33];  // [x][c2] padded stride 33
  __shared__ __align__(16) float cssp[4 * 64];
  const int t = threadIdx.x;
  if (blockIdx.y == 32) {
    wnorm_one(w, wt, wt3, blockIdx.x * 4 + (t >> 6), t & 63);
    return;
  }
  const int y = blockIdx.x, b = blockIdx.y;
  const int c = t >> 2, m = t & 3;
  const int lane = t & 63, wv = t >> 6;

  const float* src = x + (((size_t)b * 64 + c) * 64 + y) * 64 + m * 4;
  float f[16];
#pragma unroll
  for (int j4 = 0; j4 < 4; ++j4) {
    const f32x4 v = *(const f32x4*)(src + j4 * 16);
#pragma unroll
    for (int k = 0; k < 4; ++k) f[j4 * 4 + k] = v[k];
  }
  float s[16];
#pragma unroll
  for (int j = 0; j < 16; ++j) {
    float v = f[j] * f[j];
    v += __shfl_xor(v, 4);
    v += __shfl_xor(v, 8);
    v += __shfl_xor(v, 16);
    v += __shfl_xor(v, 32);
    s[j] = v;
  }
  if (lane < 4) {
#pragma unroll
    for (int j4 = 0; j4 < 4; ++j4) {
      f32x4 v = {s[j4 * 4], s[j4 * 4 + 1], s[j4 * 4 + 2], s[j4 * 4 + 3]};
      *(f32x4*)(cssp + wv * 64 + j4 * 16 + lane * 4) = v;
    }
  }
  const int parity = c & 1;
  const int c2 = c >> 1;
#pragma unroll
  for (int j = 0; j < 16; ++j) {
    const float pf = __shfl_xor(f[j], 4);
    const bool mine = parity ? (j >= 8) : (j < 8);
    if (mine) {
      const unsigned dw = parity ? (bfbits(pf) | (bfbits(f[j]) << 16))
                                 : (bfbits(f[j]) | (bfbits(pf) << 16));
      const int px = (j >> 2) * 16 + m * 4 + (j & 3);
      tile[px * 33 + c2] = dw;
    }
  }
  __syncthreads();
  // write xt c-block-major: granule (cb, x) at ((b*64+y)*8 + cb)*512 + x*8
  {
    const int xr = t & 63, q = t >> 6;
    unsigned d[8];
#pragma unroll
    for (int i = 0; i < 8; ++i) d[i] = tile[xr * 33 + q * 8 + i];
    ushort* dst =
        xt + ((((size_t)b * 64 + y) * 8 + 2 * q) * 64 + xr) * 8;
    u32x4 v0 = {d[0], d[1], d[2], d[3]};
    u32x4 v1 = {d[4], d[5], d[6], d[7]};
    *(u32x4*)dst = v0;
    *(u32x4*)(dst + 512) = v1;  // cb+1 plane
  }
  if (t < 64) {
    const float sum = cssp[t] + cssp[64 + t] + cssp[128 + t] + cssp[192 + t];
    css[((size_t)b * 64 + y) * 64 + t] = sum;
  }
}

// ---------------------------------------------------------------------------
// Main kernel (round-11 structure + depth-3 B prefetch == round-14, the
// verified best): one block per (y0, image). 8 waves = 2(M) x 4(N), wave
// tile 64x64 (acc = 64 AGPR; the max-reuse tile at the (512,4) 128-reg cap).
// A tile in LDS is C-BLOCK-MAJOR: xs[row4][cb8][col66] 16B granules ->
// A-reads stride-1, conflict-free (verified r11: 2.62M -> 262K).
// B from wt3 with DEPTH-3 register prefetch. invp from css in-kernel; exp
// epilogue fused with pool writes; 2x2 pool via transposed pool PS=258;
// coalesced 128B-row store. setprio kept (removal regressed, r12); no
// explicit A-dbuf (regressed, r12); no epilogue remap (spilled, r15); no
// 2-pass fusion (spilled, r13). This config is the measured optimum of the
// design family: latency-bound at the 128-reg/wave occupancy ceiling.
//
// LDS: xs   [4 rows][8 cb][66 cols][16B]                      [0, 33792)
//      pool [32 px][258 floats] transposed                [33792, 66816)
//      invp float[128]                                    [66816, 67328)
// ---------------------------------------------------------------------------
__global__ __launch_bounds__(512, 4) void ckn_main(
    const ushort* __restrict__ xt, const float* __restrict__ css,
    const ushort* __restrict__ wt3, float* __restrict__ out) {
  __shared__ __align__(16) char smem[67328];
  char* const xs = smem;
  float* const pool = (float*)(smem + 33792);
  float* const invp = (float*)(smem + 66816);
  const int PS = 258;

  const int tid = threadIdx.x;
  const int y0 = blockIdx.x;
  const int b = blockIdx.y;

  // ---- invp from css (rows 2y0, 2y0+1 windows), written pre-barrier ----
  if (tid < 128) {
    const int ry = tid >> 6, xx = tid & 63;
    const int yc = 2 * y0 + ry;
    float s = 0.f;
#pragma unroll
    for (int dy = -1; dy <= 1; ++dy) {
      const int yy = yc + dy;
      if ((unsigned)yy < 64u) s += css[((size_t)b * 64 + yy) * 64 + xx];
    }
    const float sl = __shfl_up(s, 1);
    const float sr = __shfl_down(s, 1);
    const float tot = s + ((xx > 0) ? sl : 0.f) + ((xx < 63) ? sr : 0.f);
    invp[tid] = 1.0f / (sqrtf(fmaxf(tot, 0.f)) + 1e-8f);
  }

  // ---- pad columns (col 0 and 65 of every (row, cb) plane) ----
  if (tid < 64) {
    const int r4 = tid >> 4, cb = (tid >> 1) & 7, colsel = tid & 1;
    *(f32x4*)(xs + r4 * 8448 + cb * 1056 + colsel * 65 * 16) =
        (f32x4){0.f, 0.f, 0.f, 0.f};
  }

  // ---- stage 4 rows: wave w stages cb-plane w of each row ----
  {
    const int l = tid & 63;   // col-1
    const int w = tid >> 6;   // cb plane
    const ushort* srcb = xt + (((size_t)b * 64) * 8 + w) * 512 + l * 8;
#pragma unroll
    for (int r4 = 0; r4 < 4; ++r4) {
      const int y_img = 2 * y0 - 1 + r4;
      char* dst = xs + r4 * 8448 + w * 1056 + (l + 1) * 16;
      if ((unsigned)y_img < 64u) {
        const ushort* src = srcb + (size_t)y_img * 4096;
        __builtin_amdgcn_global_load_lds(
            (const __attribute__((address_space(1))) void*)src,
            (__attribute__((address_space(3))) void*)dst, 16, 0, 0);
      } else {
        *(f32x4*)dst = (f32x4){0.f, 0.f, 0.f, 0.f};
      }
    }
  }

  const int lane = tid & 63;
  const int wid = tid >> 6;
  const int wave_m = wid & 1;   // output row within pair (m-half)
  const int wave_n = wid >> 1;  // 64-wide N chunk
  const int lane31 = lane & 31;
  const int hi = lane >> 5;

  // B base in wt3 (ushort elems): fragment (ks, g) is 512 shorts at
  // (ks*8+g)*512; lane reads 8 shorts at n*16 + hi*8.
  const ushort* wb3 = wt3 + (size_t)lane31 * 16 + hi * 8;
  const int g0 = wave_n * 2;

  // DEPTH-3 B prefetch: ks=0,1,2 issued BEFORE the barrier (overlaps DMA).
  bf16x8 bq[3][2];
#pragma unroll
  for (int d = 0; d < 3; ++d)
#pragma unroll
    for (int nf = 0; nf < 2; ++nf)
      bq[d][nf] = *(const bf16x8*)(wb3 + (size_t)(d * 8 + g0 + nf) * 512);

  // A base addresses: PH[mf][kw] = (mf*32+lane31+kw)*16 + hi*1056 + wave_m*8448
  // per-step addr = PH + kh*8448 + (ks&3)*2112  (compile-time per step)
  int PH[2][3];
#pragma unroll
  for (int mf = 0; mf < 2; ++mf)
#pragma unroll
    for (int kw = 0; kw < 3; ++kw)
      PH[mf][kw] =
          (mf * 32 + lane31 + kw) * 16 + hi * 1056 + wave_m * 8448;

  __syncthreads();

  f32x16 acc[2][2];
#pragma unroll
  for (int i = 0; i < 2; ++i)
#pragma unroll
    for (int j = 0; j < 2; ++j)
#pragma unroll
      for (int e = 0; e < 16; ++e) acc[i][j][e] = 0.f;

#pragma unroll
  for (int ks = 0; ks < 36; ++ks) {
    const int t9 = ks >> 2;
    const int kh = t9 / 3, kw = t9 % 3;
    const int stepoff = kh * 8448 + (ks & 3) * 2112;  // compile-time const
    const int cur = ks % 3;                            // compile-time const
    bf16x8 afrag[2];
#pragma unroll
    for (int mf = 0; mf < 2; ++mf)
      afrag[mf] = *(const bf16x8*)(xs + PH[mf][kw] + stepoff);
    __builtin_amdgcn_s_setprio(1);
#pragma unroll
    for (int mf = 0; mf < 2; ++mf)
#pragma unroll
      for (int nf = 0; nf < 2; ++nf)
        acc[mf][nf] = __builtin_amdgcn_mfma_f32_32x32x16_bf16(
            afrag[mf], bq[cur][nf], acc[mf][nf], 0, 0, 0);
    __builtin_amdgcn_s_setprio(0);
    if (ks + 3 < 36) {
#pragma unroll
      for (int nf = 0; nf < 2; ++nf)
        bq[cur][nf] =
            *(const bf16x8*)(wb3 + (size_t)((ks + 3) * 8 + g0 + nf) * 512);
    }
  }

  // ---- epilogue: exp(cos-1) fused with pool writes (transposed pool) ----
  // acc reg r: x = mf*32 + (r&3) + 8*(r>>2) + 4*hi ; o = wave_n*64+nf*32+lane31
  if (wave_m == 1) {
#pragma unroll
    for (int mf = 0; mf < 2; ++mf)
#pragma unroll
      for (int q = 0; q < 4; ++q) {
        const f32x4 ip = *(const f32x4*)(invp + 64 + mf * 32 + 8 * q + 4 * hi);
        const int px = mf * 16 + 4 * q + 2 * hi;
#pragma unroll
        for (int nf = 0; nf < 2; ++nf) {
          const int o = wave_n * 64 + nf * 32 + lane31;
          const float e0 = __expf(acc[mf][nf][4 * q + 0] * ip[0] - 1.f);
          const float e1 = __expf(acc[mf][nf][4 * q + 1] * ip[1] - 1.f);
          const float e2 = __expf(acc[mf][nf][4 * q + 2] * ip[2] - 1.f);
          const float e3 = __expf(acc[mf][nf][4 * q + 3] * ip[3] - 1.f);
          pool[px * PS + o] = e0 + e1;
          pool[(px + 1) * PS + o] = e2 + e3;
        }
      }
  }
  __syncthreads();
  if (wave_m == 0) {
#pragma unroll
    for (int mf = 0; mf < 2; ++mf)
#pragma unroll
      for (int q = 0; q < 4; ++q) {
        const f32x4 ip = *(const f32x4*)(invp + mf * 32 + 8 * q + 4 * hi);
        const int px = mf * 16 + 4 * q + 2 * hi;
#pragma unroll
        for (int nf = 0; nf < 2; ++nf) {
          const int o = wave_n * 64 + nf * 32 + lane31;
          const float e0 = __expf(acc[mf][nf][4 * q + 0] * ip[0] - 1.f);
          const float e1 = __expf(acc[mf][nf][4 * q + 1] * ip[1] - 1.f);
          const float e2 = __expf(acc[mf][nf][4 * q + 2] * ip[2] - 1.f);
          const float e3 = __expf(acc[mf][nf][4 * q + 3] * ip[3] - 1.f);
          pool[px * PS + o] = 0.25f * (pool[px * PS + o] + e0 + e1);
          pool[(px + 1) * PS + o] = 0.25f * (pool[(px + 1) * PS + o] + e2 + e3);
        }
      }
  }
  __syncthreads();

  // ---- coalesced store: 8 lanes cover one o-row's full 128B ----
  const size_t obase = (((size_t)b * 256) * 32 + y0) * 32;
#pragma unroll
  for (int j = 0; j < 4; ++j) {
    const int o = j * 64 + (tid >> 3);
    const int ch = (tid & 7) * 4;
    const f32x4 v = {pool[(ch + 0) * PS + o], pool[(ch + 1) * PS + o],
                     pool[(ch + 2) * PS + o], pool[(ch + 3) * PS + o]};
    *(f32x4*)(out + obase + (size_t)o * 1024 + ch) = v;
  }
}

// ---------------------------------------------------------------------------
// Fallback (round-1 kernel, fused transpose in-block) if ws is too small.
// ---------------------------------------------------------------------------
__global__ __launch_bounds__(512, 4) void ckn_main_v1(
    const float* __restrict__ x, const ushort* __restrict__ wt,
    float* __restrict__ out) {
  __shared__ __align__(16) char smem[43552];
  char* const xs = smem;
  float* const invp = (float*)(smem + 33792);
  float* const cs = (float*)(smem + 34304);
  float* const csp = (float*)(smem + 35360);
  float* const pool = (float*)smem;

  const int tid = threadIdx.x;
  const int y0 = blockIdx.x;
  const int b = blockIdx.y;

  if (tid < 64) {
    const int r4 = tid >> 4, colsel = (tid >> 3) & 1, cblk = tid & 7;
    const int col = colsel * 65;
    *(f32x4*)(xs + r4 * 8448 + col * 128 + cblk * 16) =
        (f32x4){0.f, 0.f, 0.f, 0.f};
  }
  {
    const int xx = tid & 63;
    const int cg = tid >> 6;
    const int col = xx + 1;
    const int sw = (cg * 16) ^ ((col & 7) << 4);
#pragma unroll
    for (int r4 = 0; r4 < 4; ++r4) {
      const int y_img = 2 * y0 - 1 + r4;
      char* dst = xs + r4 * 8448 + col * 128 + sw;
      if ((unsigned)y_img < 64u) {
        const float* src =
            x + (((size_t)b * 64 + cg * 8) * 64 + y_img) * 64 + xx;
        float ss = 0.f;
        union { bf16x8 v; ushort u[8]; } pk;
#pragma unroll
        for (int j = 0; j < 8; ++j) {
          const float f = src[(size_t)j * 4096];
          ss += f * f;
          pk.u[j] = (ushort)bfbits(f);
        }
        *(bf16x8*)dst = pk.v;
        csp[(r4 * 8 + cg) * 64 + xx] = ss;
      } else {
        *(bf16x8*)dst = (bf16x8){0, 0, 0, 0, 0, 0, 0, 0};
        csp[(r4 * 8 + cg) * 64 + xx] = 0.f;
      }
    }
  }
  __syncthreads();
  if (tid < 256) {
    const int r4 = tid >> 6, xc = tid & 63;
    float s = 0.f;
#pragma unroll
    for (int cg = 0; cg < 8; ++cg) s += csp[(r4 * 8 + cg) * 64 + xc];
    cs[r4 * 66 + xc + 1] = s;
  }
  if (tid >= 256 && tid < 264) {
    const int t = tid - 256;
    cs[(t >> 1) * 66 + (t & 1) * 65] = 0.f;
  }
  __syncthreads();
  if (tid < 128) {
    const int ry = tid >> 6, xp = tid & 63;
    float s = 0.f;
#pragma unroll
    for (int dr = 0; dr < 3; ++dr)
#pragma unroll
      for (int dc = 0; dc < 3; ++dc) s += cs[(ry + dr) * 66 + xp + dc];
    invp[tid] = 1.0f / (sqrtf(fmaxf(s, 0.f)) + 1e-8f);
  }
  __syncthreads();

  const int lane = tid & 63;
  const int wid = tid >> 6;
  const int wave_m = wid & 1;
  const int wave_n = wid >> 1;
  const int lane16 = lane & 15;
  const int klane = lane >> 4;
  const int o_base = wave_n * 64;

  f32x4 acc[4][4];
#pragma unroll
  for (int i = 0; i < 4; ++i)
#pragma unroll
    for (int j = 0; j < 4; ++j) acc[i][j] = (f32x4){0.f, 0.f, 0.f, 0.f};
  const ushort* wbase = wt + (o_base + lane16) * 576 + klane * 8;
#pragma unroll
  for (int ks = 0; ks < 18; ++ks) {
    const int t9 = ks >> 1;
    const int kh = t9 / 3, kw = t9 % 3;
    const int cb = (ks & 1) * 64 + klane * 16;
    bf16x8 bfrag[4];
#pragma unroll
    for (int fn = 0; fn < 4; ++fn)
      bfrag[fn] = *(const bf16x8*)(wbase + fn * 16 * 576 + ks * 32);
    const int r4 = wave_m + kh;
#pragma unroll
    for (int fm = 0; fm < 4; ++fm) {
      const int col = fm * 16 + lane16 + kw;
      const int addr = r4 * 8448 + col * 128 + (cb ^ ((col & 7) << 4));
      const bf16x8 afrag = *(const bf16x8*)(xs + addr);
#pragma unroll
      for (int fn = 0; fn < 4; ++fn)
        acc[fm][fn] = __builtin_amdgcn_mfma_f32_16x16x32_bf16(
            afrag, bfrag[fn], acc[fm][fn], 0, 0, 0);
    }
  }
  float ep0[4][4], ep1[4][4];
#pragma unroll
  for (int fm = 0; fm < 4; ++fm) {
    const int m = wave_m * 64 + fm * 16 + klane * 4;
    const f32x4 ip = *(const f32x4*)(invp + m);
#pragma unroll
    for (int fn = 0; fn < 4; ++fn) {
      const f32x4 v = acc[fm][fn];
      const float e0 = __expf(v[0] * ip[0] - 1.f);
      const float e1 = __expf(v[1] * ip[1] - 1.f);
      const float e2 = __expf(v[2] * ip[2] - 1.f);
      const float e3 = __expf(v[3] * ip[3] - 1.f);
      ep0[fm][fn] = e0 + e1;
      ep1[fm][fn] = e2 + e3;
    }
  }
  __syncthreads();
  if (wave_m == 1) {
#pragma unroll
    for (int fm = 0; fm < 4; ++fm) {
      const int ox = fm * 8 + klane * 2;
#pragma unroll
      for (int fn = 0; fn < 4; ++fn) {
        const int o = o_base + fn * 16 + lane16;
        *(float2*)(pool + o * 32 + ox) = make_float2(ep0[fm][fn], ep1[fm][fn]);
      }
    }
  }
  __syncthreads();
  if (wave_m == 0) {
#pragma unroll
    for (int fm = 0; fm < 4; ++fm) {
      const int ox = fm * 8 + klane * 2;
#pragma unroll
      for (int fn = 0; fn < 4; ++fn) {
        const int o = o_base + fn * 16 + lane16;
        const float2 othr = *(const float2*)(pool + o * 32 + ox);
        const float r0 = 0.25f * (ep0[fm][fn] + othr.x);
        const float r1 = 0.25f * (ep1[fm][fn] + othr.y);
        *(float2*)(out + ((((size_t)b * 256 + o) * 32 + y0) * 32 + ox)) =
            make_float2(r0, r1);
      }
    }
  }
}

// ---------------------------------------------------------------------------
extern "C" void kernel_launch(void* const* d_in, const int* in_sizes, int n_in,
                              void* d_out, int out_size, void* d_ws,
                              size_t ws_size, hipStream_t stream) {
  const float* x = (const float*)d_in[0];
  const float* w = (const float*)d_in[1];
  float* out = (float*)d_out;

  const size_t XT_BYTES = 32ull * 64 * 64 * 64 * 2;   // 16,777,216
  const size_t CSS_BYTES = 32ull * 64 * 64 * 4;       //    524,288
  const size_t WT_BYTES = 256ull * 576 * 2;           //    294,912
  const size_t NEED = XT_BYTES + CSS_BYTES + 2 * WT_BYTES;

  if (ws_size >= NEED) {
    ushort* xt = (ushort*)d_ws;
    float* css = (float*)((char*)d_ws + XT_BYTES);
    ushort* wt = (ushort*)((char*)d_ws + XT_BYTES + CSS_BYTES);
    ushort* wt3 = (ushort*)((char*)d_ws + XT_BYTES + CSS_BYTES + WT_BYTES);

    xprep_kernel<<<dim3(64, 33), dim3(256), 0, stream>>>(x, xt, css, w, wt,
                                                         wt3);
    ckn_main<<<dim3(32, 32), dim3(512), 0, stream>>>(xt, css, wt3, out);
  } else {
    ushort* wt = (ushort*)d_ws;
    ushort* wt3 = wt + 256 * 576;
    if (ws_size >= 2 * WT_BYTES) {
      wnorm_kernel<<<dim3(256), dim3(64), 0, stream>>>(w, wt, wt3);
      ckn_main_v1<<<dim3(32, 32), dim3(512), 0, stream>>>(x, wt, out);
    }
  }
}